// Round 1
// baseline (539.346 us; speedup 1.0000x reference)
//
#include <hip/hip_runtime.h>
#include <stdint.h>

#define T_SEQ 2048
#define DMODEL 1024
#define NHEAD 16
#define HS 64
#define N3 3072
#define BSZ 4
#define MTOT (BSZ*T_SEQ)   // 8192

typedef __attribute__((ext_vector_type(8))) short bf16x8;
typedef __attribute__((ext_vector_type(4))) float f32x4;

// 0.125 (1/sqrt(64)) * log2(e): folded into Q so softmax runs in exp2 domain
#define QSCALE 0.18033688011112042f

__device__ inline unsigned short f2bf(float f){
  union { float f; uint32_t u; } v; v.f = f;
  uint32_t r = (v.u + 0x7fffu + ((v.u >> 16) & 1u)) >> 16;
  return (unsigned short)r;
}

__device__ inline void gld16(const void* g, void* l){
  __builtin_amdgcn_global_load_lds((const __attribute__((address_space(1))) void*)g,
                                   (__attribute__((address_space(3))) void*)l, 16, 0, 0);
}

// ---- fp32 -> bf16 convert (x) ----
__global__ __launch_bounds__(256) void cvt_x(const float* __restrict__ x,
                                             unsigned short* __restrict__ xb, int n){
  int stride = gridDim.x * blockDim.x;
  for (int i = blockIdx.x * blockDim.x + threadIdx.x; i * 4 < n; i += stride){
    const float4 v = *(const float4*)(x + (size_t)i * 4);
    ushort4 o; o.x = f2bf(v.x); o.y = f2bf(v.y); o.z = f2bf(v.z); o.w = f2bf(v.w);
    *(ushort4*)(xb + (size_t)i * 4) = o;
  }
}

// ---- W [1024][3072] fp32 -> Wt [3072][1024] bf16 (tiled transpose) ----
__global__ __launch_bounds__(256) void cvt_wt(const float* __restrict__ W,
                                              unsigned short* __restrict__ Wt){
  __shared__ float tile[32][33];
  int bx = blockIdx.x;  // n tile (0..95)
  int by = blockIdx.y;  // k tile (0..31)
  int tx = threadIdx.x; // 0..31
  int ty = threadIdx.y; // 0..7
#pragma unroll
  for (int i = 0; i < 4; i++){
    int k = by * 32 + ty + i * 8;
    int n = bx * 32 + tx;
    tile[ty + i * 8][tx] = W[(size_t)k * N3 + n];
  }
  __syncthreads();
#pragma unroll
  for (int i = 0; i < 4; i++){
    int n = bx * 32 + ty + i * 8;
    int k = by * 32 + tx;
    Wt[(size_t)n * DMODEL + k] = f2bf(tile[tx][ty + i * 8]);
  }
}

// ---- QKV projection GEMM: C[8192][3072] = xb * Wt^T + bias, scattered to Q/K/Vt ----
#define BM 128
#define BN 128
#define BK 32

__global__ __launch_bounds__(256, 2) void gemm_qkv(
    const unsigned short* __restrict__ xb, const unsigned short* __restrict__ wt,
    const float* __restrict__ bias,
    unsigned short* __restrict__ Qb, unsigned short* __restrict__ Kb,
    unsigned short* __restrict__ Vt)
{
  __shared__ unsigned short Al[BM * BK];
  __shared__ unsigned short Bl[BN * BK];
  const int tid = threadIdx.x;
  const int lane = tid & 63;
  const int w  = tid >> 6;
  const int wm = w >> 1, wn = w & 1;
  const int lr = lane & 15, lg = lane >> 4;
  const int m0 = blockIdx.x * BM;
  const int n0 = blockIdx.y * BN;

  f32x4 acc[4][4] = {};

  const int srow = tid >> 2;          // 0..63
  const int scol = (tid & 3) * 8;     // 0,8,16,24
  const unsigned short* ga0 = xb + (size_t)(m0 + srow) * DMODEL + scol;
  const unsigned short* gb0 = wt + (size_t)(n0 + srow) * DMODEL + scol;
  unsigned short* la = &Al[tid * 8];
  unsigned short* lb = &Bl[tid * 8];

  for (int k0 = 0; k0 < DMODEL; k0 += BK){
    gld16(ga0 + k0, la);
    gld16(ga0 + k0 + (size_t)64 * DMODEL, la + 2048);
    gld16(gb0 + k0, lb);
    gld16(gb0 + k0 + (size_t)64 * DMODEL, lb + 2048);
    __syncthreads();
    bf16x8 af[4], bfg[4];
#pragma unroll
    for (int i = 0; i < 4; i++){
      af[i]  = *(const bf16x8*)&Al[(wm * 64 + i * 16 + lr) * BK + lg * 8];
      bfg[i] = *(const bf16x8*)&Bl[(wn * 64 + i * 16 + lr) * BK + lg * 8];
    }
#pragma unroll
    for (int i = 0; i < 4; i++)
#pragma unroll
      for (int j = 0; j < 4; j++)
        acc[i][j] = __builtin_amdgcn_mfma_f32_16x16x32_bf16(af[i], bfg[j], acc[i][j], 0, 0, 0);
    __syncthreads();
  }

  // epilogue: bias + scatter into Q (scaled), K, V^T
#pragma unroll
  for (int i = 0; i < 4; i++){
#pragma unroll
    for (int j = 0; j < 4; j++){
      int gn = n0 + wn * 64 + j * 16 + lr;
      float bv = bias[gn];
      int h = gn / 192;
      int rem = gn - h * 192;
      int which = rem >> 6;
      int d = rem & 63;
#pragma unroll
      for (int r = 0; r < 4; r++){
        int gm = m0 + wm * 64 + i * 16 + lg * 4 + r;
        int b = gm >> 11, t = gm & 2047;
        float val = acc[i][j][r] + bv;
        size_t bh = (size_t)(b * NHEAD + h);
        if (which == 0)      Qb[(bh * T_SEQ + t) * HS + d] = f2bf(val * QSCALE);
        else if (which == 1) Kb[(bh * T_SEQ + t) * HS + d] = f2bf(val);
        else                 Vt[(bh * HS + d) * T_SEQ + t] = f2bf(val);
      }
    }
  }
}

// ---- flash attention: grid (T/64, nh, bs), 4 waves, each wave 16 q-rows ----
__global__ __launch_bounds__(256, 4) void attn(
    const unsigned short* __restrict__ Qb, const unsigned short* __restrict__ Kb,
    const unsigned short* __restrict__ Vt, float* __restrict__ out)
{
  __shared__ unsigned short Pl[4][16 * 32];
  const int tid = threadIdx.x;
  const int lane = tid & 63;
  const int w = tid >> 6;
  const int lr = lane & 15, lg = lane >> 4;
  const int b = blockIdx.z, h = blockIdx.y;
  const int bh = b * NHEAD + h;
  const unsigned short* Qh = Qb + (size_t)bh * T_SEQ * HS;
  const unsigned short* Kh = Kb + (size_t)bh * T_SEQ * HS;
  const unsigned short* Vh = Vt + (size_t)bh * HS * T_SEQ;
  const int q0 = blockIdx.x * 64 + w * 16;

  bf16x8 aq[2];
  aq[0] = *(const bf16x8*)(Qh + (size_t)(q0 + lr) * HS + lg * 8);
  aq[1] = *(const bf16x8*)(Qh + (size_t)(q0 + lr) * HS + 32 + lg * 8);

  float m_[4], l_[4];
  f32x4 acc[4] = {};
#pragma unroll
  for (int r = 0; r < 4; r++){ m_[r] = -1e30f; l_[r] = 0.f; }
  unsigned short* pw = &Pl[w][0];

  for (int kv0 = 0; kv0 < T_SEQ; kv0 += 32){
    f32x4 s[2] = {};
#pragma unroll
    for (int j = 0; j < 2; j++){
      const unsigned short* kp = Kh + (size_t)(kv0 + j * 16 + lr) * HS + lg * 8;
      bf16x8 kv0v = *(const bf16x8*)kp;
      bf16x8 kv1v = *(const bf16x8*)(kp + 32);
      s[j] = __builtin_amdgcn_mfma_f32_16x16x32_bf16(aq[0], kv0v, s[j], 0, 0, 0);
      s[j] = __builtin_amdgcn_mfma_f32_16x16x32_bf16(aq[1], kv1v, s[j], 0, 0, 0);
    }
    float bm[4], rs[4], alpha[4];
#pragma unroll
    for (int r = 0; r < 4; r++) bm[r] = fmaxf(s[0][r], s[1][r]);
#pragma unroll
    for (int off = 8; off >= 1; off >>= 1)
#pragma unroll
      for (int r = 0; r < 4; r++) bm[r] = fmaxf(bm[r], __shfl_xor(bm[r], off));
#pragma unroll
    for (int r = 0; r < 4; r++){
      float mn = fmaxf(m_[r], bm[r]);
      alpha[r] = __builtin_amdgcn_exp2f(m_[r] - mn);
      m_[r] = mn;
    }
#pragma unroll
    for (int r = 0; r < 4; r++){
      float p0 = __builtin_amdgcn_exp2f(s[0][r] - m_[r]);
      float p1 = __builtin_amdgcn_exp2f(s[1][r] - m_[r]);
      pw[(lg * 4 + r) * 32 + lr]      = f2bf(p0);
      pw[(lg * 4 + r) * 32 + 16 + lr] = f2bf(p1);
      rs[r] = p0 + p1;
    }
#pragma unroll
    for (int off = 8; off >= 1; off >>= 1)
#pragma unroll
      for (int r = 0; r < 4; r++) rs[r] += __shfl_xor(rs[r], off);
#pragma unroll
    for (int r = 0; r < 4; r++) l_[r] = l_[r] * alpha[r] + rs[r];
#pragma unroll
    for (int nt = 0; nt < 4; nt++)
#pragma unroll
      for (int r = 0; r < 4; r++) acc[nt][r] *= alpha[r];

    bf16x8 pa = *(const bf16x8*)&pw[lr * 32 + lg * 8];
#pragma unroll
    for (int nt = 0; nt < 4; nt++){
      bf16x8 bv = *(const bf16x8*)(Vh + (size_t)(nt * 16 + lr) * T_SEQ + kv0 + lg * 8);
      acc[nt] = __builtin_amdgcn_mfma_f32_16x16x32_bf16(pa, bv, acc[nt], 0, 0, 0);
    }
  }

  float inv[4];
#pragma unroll
  for (int r = 0; r < 4; r++) inv[r] = 1.0f / l_[r];
#pragma unroll
  for (int nt = 0; nt < 4; nt++){
    int d = nt * 16 + lr;
#pragma unroll
    for (int r = 0; r < 4; r++){
      int q = q0 + lg * 4 + r;
      out[((size_t)(b * T_SEQ + q)) * DMODEL + h * HS + d] = acc[nt][r] * inv[r];
    }
  }
}

extern "C" void kernel_launch(void* const* d_in, const int* in_sizes, int n_in,
                              void* d_out, int out_size, void* d_ws, size_t ws_size,
                              hipStream_t stream) {
  const float* x  = (const float*)d_in[0];
  const float* Wq = (const float*)d_in[1];
  const float* bq = (const float*)d_in[2];
  float* out = (float*)d_out;
  uint8_t* ws = (uint8_t*)d_ws;

  // workspace layout (bytes): xb 16MB | wt 6MB | Q 16MB | K 16MB | Vt 16MB = 70MB
  unsigned short* xb = (unsigned short*)(ws);
  unsigned short* wt = (unsigned short*)(ws + (size_t)16 * 1024 * 1024);
  unsigned short* Qb = (unsigned short*)(ws + (size_t)22 * 1024 * 1024);
  unsigned short* Kb = (unsigned short*)(ws + (size_t)38 * 1024 * 1024);
  unsigned short* Vt = (unsigned short*)(ws + (size_t)54 * 1024 * 1024);

  cvt_x<<<2048, 256, 0, stream>>>(x, xb, MTOT * DMODEL);
  cvt_wt<<<dim3(N3 / 32, DMODEL / 32), dim3(32, 8), 0, stream>>>(Wq, wt);
  gemm_qkv<<<dim3(MTOT / BM, N3 / BN), 256, 0, stream>>>(xb, wt, bq, Qb, Kb, Vt);
  attn<<<dim3(T_SEQ / 64, NHEAD, BSZ), 256, 0, stream>>>(Qb, Kb, Vt, out);
}

// Round 2
// 317.959 us; speedup vs baseline: 1.6963x; 1.6963x over previous
//
#include <hip/hip_runtime.h>
#include <stdint.h>

#define T_SEQ 2048
#define DMODEL 1024
#define NHEAD 16
#define HS 64
#define N3 3072
#define BSZ 4
#define MTOT (BSZ*T_SEQ)   // 8192

typedef __attribute__((ext_vector_type(8))) short bf16x8;
typedef __attribute__((ext_vector_type(4))) float f32x4;
typedef __attribute__((ext_vector_type(16))) float f32x16;
typedef __attribute__((ext_vector_type(2))) unsigned int uint2v;

// 0.125 (1/sqrt(64)) * log2(e): folded into Q so softmax runs in exp2 domain
#define QSCALE 0.18033688011112042f

__device__ inline unsigned short f2bf(float f){
  union { float f; uint32_t u; } v; v.f = f;
  uint32_t r = (v.u + 0x7fffu + ((v.u >> 16) & 1u)) >> 16;
  return (unsigned short)r;
}

__device__ inline uint32_t cvtpk_bf16(float lo, float hi){
  uint32_t r;
  asm("v_cvt_pk_bf16_f32 %0, %1, %2" : "=v"(r) : "v"(lo), "v"(hi));
  return r;
}

// permlane32_swap: a' = {a.lo(l0-31), b.lo(l32-63)}, b' = {a.hi(l0-31), b.hi(l32-63)}
__device__ inline void plswap(uint32_t &a, uint32_t &b){
  uint2v r = __builtin_amdgcn_permlane32_swap(a, b, false, false);
  a = r[0]; b = r[1];
}

__device__ inline void gld16(const void* g, void* l){
  __builtin_amdgcn_global_load_lds((const __attribute__((address_space(1))) void*)g,
                                   (__attribute__((address_space(3))) void*)l, 16, 0, 0);
}

// ---- fp32 -> bf16 convert (x) ----
__global__ __launch_bounds__(256) void cvt_x(const float* __restrict__ x,
                                             unsigned short* __restrict__ xb, int n){
  int stride = gridDim.x * blockDim.x;
  for (int i = blockIdx.x * blockDim.x + threadIdx.x; i * 4 < n; i += stride){
    const float4 v = *(const float4*)(x + (size_t)i * 4);
    ushort4 o; o.x = f2bf(v.x); o.y = f2bf(v.y); o.z = f2bf(v.z); o.w = f2bf(v.w);
    *(ushort4*)(xb + (size_t)i * 4) = o;
  }
}

// ---- W [1024][3072] fp32 -> Wt [3072][1024] bf16 (tiled transpose) ----
__global__ __launch_bounds__(256) void cvt_wt(const float* __restrict__ W,
                                              unsigned short* __restrict__ Wt){
  __shared__ float tile[32][33];
  int bx = blockIdx.x;  // n tile
  int by = blockIdx.y;  // k tile
  int tx = threadIdx.x; // 0..31
  int ty = threadIdx.y; // 0..7
#pragma unroll
  for (int i = 0; i < 4; i++){
    int k = by * 32 + ty + i * 8;
    int n = bx * 32 + tx;
    tile[ty + i * 8][tx] = W[(size_t)k * N3 + n];
  }
  __syncthreads();
#pragma unroll
  for (int i = 0; i < 4; i++){
    int n = bx * 32 + ty + i * 8;
    int k = by * 32 + tx;
    Wt[(size_t)n * DMODEL + k] = f2bf(tile[tx][ty + i * 8]);
  }
}

// ---- QKV projection GEMM: C[8192][3072] = xb * Wt^T + bias, scattered to Q/K/Vt ----
#define BM 128
#define BN 128
#define BK 32

__global__ __launch_bounds__(256, 2) void gemm_qkv(
    const unsigned short* __restrict__ xb, const unsigned short* __restrict__ wt,
    const float* __restrict__ bias,
    unsigned short* __restrict__ Qb, unsigned short* __restrict__ Kb,
    unsigned short* __restrict__ Vt)
{
  __shared__ unsigned short Al[BM * BK];
  __shared__ unsigned short Bl[BN * BK];
  const int tid = threadIdx.x;
  const int lane = tid & 63;
  const int w  = tid >> 6;
  const int wm = w >> 1, wn = w & 1;
  const int lr = lane & 15, lg = lane >> 4;
  const int m0 = blockIdx.x * BM;
  const int n0 = blockIdx.y * BN;

  f32x4 acc[4][4] = {};

  const int srow = tid >> 2;
  const int scol = (tid & 3) * 8;
  const unsigned short* ga0 = xb + (size_t)(m0 + srow) * DMODEL + scol;
  const unsigned short* gb0 = wt + (size_t)(n0 + srow) * DMODEL + scol;
  unsigned short* la = &Al[tid * 8];
  unsigned short* lb = &Bl[tid * 8];

  for (int k0 = 0; k0 < DMODEL; k0 += BK){
    gld16(ga0 + k0, la);
    gld16(ga0 + k0 + (size_t)64 * DMODEL, la + 2048);
    gld16(gb0 + k0, lb);
    gld16(gb0 + k0 + (size_t)64 * DMODEL, lb + 2048);
    __syncthreads();
    bf16x8 af[4], bfg[4];
#pragma unroll
    for (int i = 0; i < 4; i++){
      af[i]  = *(const bf16x8*)&Al[(wm * 64 + i * 16 + lr) * BK + lg * 8];
      bfg[i] = *(const bf16x8*)&Bl[(wn * 64 + i * 16 + lr) * BK + lg * 8];
    }
#pragma unroll
    for (int i = 0; i < 4; i++)
#pragma unroll
      for (int j = 0; j < 4; j++)
        acc[i][j] = __builtin_amdgcn_mfma_f32_16x16x32_bf16(af[i], bfg[j], acc[i][j], 0, 0, 0);
    __syncthreads();
  }

#pragma unroll
  for (int i = 0; i < 4; i++){
#pragma unroll
    for (int j = 0; j < 4; j++){
      int gn = n0 + wn * 64 + j * 16 + lr;
      float bv = bias[gn];
      int h = gn / 192;
      int rem = gn - h * 192;
      int which = rem >> 6;
      int d = rem & 63;
#pragma unroll
      for (int r = 0; r < 4; r++){
        int gm = m0 + wm * 64 + i * 16 + lg * 4 + r;
        int b = gm >> 11, t = gm & 2047;
        float val = acc[i][j][r] + bv;
        size_t bh = (size_t)(b * NHEAD + h);
        if (which == 0)      Qb[(bh * T_SEQ + t) * HS + d] = f2bf(val * QSCALE);
        else if (which == 1) Kb[(bh * T_SEQ + t) * HS + d] = f2bf(val);
        else                 Vt[(bh * HS + d) * T_SEQ + t] = f2bf(val);
      }
    }
  }
}

// ---- flash attention, swapped-operand 32x32 MFMA, in-register softmax ----
// grid (16,16,4) -> XCD-swizzled; block = 4 waves, each wave owns 32 q rows.
__global__ __launch_bounds__(256, 4) void attn(
    const unsigned short* __restrict__ Qb, const unsigned short* __restrict__ Kb,
    const unsigned short* __restrict__ Vt, float* __restrict__ out)
{
  __shared__ float tl[4][64 * 33];

  // XCD-bijective swizzle: 1024 wgs, 8 XCDs -> 128 contiguous work ids per XCD
  int flat = blockIdx.x + (blockIdx.y << 4) + (blockIdx.z << 8);
  int wid = (flat & 7) * 128 + (flat >> 3);
  const int bx = wid & 15;
  const int h  = (wid >> 4) & 15;
  const int b  = wid >> 8;

  const int tid = threadIdx.x;
  const int lane = tid & 63;
  const int w = tid >> 6;
  const int ql = lane & 31;   // this lane's q (and V-row d) index
  const int hi = lane >> 5;
  const int bh = b * NHEAD + h;
  const int q0 = bx * 128 + w * 32;

  const unsigned short* Qh = Qb + (size_t)bh * T_SEQ * HS;
  const unsigned short* Kh = Kb + (size_t)bh * T_SEQ * HS;
  const unsigned short* Vh = Vt + (size_t)bh * HS * T_SEQ;

  // Q fragments (B operand): Q[q0+ql][c*16 + hi*8 + e]
  bf16x8 qf[4];
#pragma unroll
  for (int c = 0; c < 4; c++)
    qf[c] = *(const bf16x8*)(Qh + (size_t)(q0 + ql) * HS + c * 16 + hi * 8);

  // K fragments (A operand) for kv0=0
  bf16x8 kf[4];
#pragma unroll
  for (int c = 0; c < 4; c++)
    kf[c] = *(const bf16x8*)(Kh + (size_t)ql * HS + c * 16 + hi * 8);

  f32x16 accT[2] = {};
  float m_ = -1e30f, l_ = 0.f;

  for (int kv0 = 0; kv0 < T_SEQ; kv0 += 32){
    // S^T[kk][q] = sum_d K[kv0+kk][d] * Q[q0+q][d]; lane: q=ql, kk=(r&3)+8*(r>>2)+4*hi
    f32x16 s = {};
#pragma unroll
    for (int c = 0; c < 4; c++)
      s = __builtin_amdgcn_mfma_f32_32x32x16_bf16(kf[c], qf[c], s, 0, 0, 0);

    // issue V loads (A operand of PV): V^T[t*32+ql][kv0 + c*16 + hi*8]
    bf16x8 vf[2][2];
#pragma unroll
    for (int t = 0; t < 2; t++)
#pragma unroll
      for (int c = 0; c < 2; c++)
        vf[t][c] = *(const bf16x8*)(Vh + (size_t)(t * 32 + ql) * T_SEQ + kv0 + c * 16 + hi * 8);

    // issue next-step K loads into kf (wrapped addr avoids branch; last iter harmless)
    int kvn = (kv0 + 32) & (T_SEQ - 1);
#pragma unroll
    for (int c = 0; c < 4; c++)
      kf[c] = *(const bf16x8*)(Kh + (size_t)(kvn + ql) * HS + c * 16 + hi * 8);

    // ---- in-register online softmax (per lane: one q, 16 of 32 kk) ----
    float t0 = fmaxf(s[0], s[1]),  t1 = fmaxf(s[2], s[3]);
    float t2 = fmaxf(s[4], s[5]),  t3 = fmaxf(s[6], s[7]);
    float t4 = fmaxf(s[8], s[9]),  t5 = fmaxf(s[10], s[11]);
    float t6 = fmaxf(s[12], s[13]), t7 = fmaxf(s[14], s[15]);
    t0 = fmaxf(t0, t1); t2 = fmaxf(t2, t3); t4 = fmaxf(t4, t5); t6 = fmaxf(t6, t7);
    t0 = fmaxf(t0, t2); t4 = fmaxf(t4, t6);
    float bm = fmaxf(t0, t4);
    bm = fmaxf(bm, __shfl_xor(bm, 32));   // combine the two kk-halves

    if (!__all(bm <= m_ + 8.f)){          // defer-max (T13)
      float mn = fmaxf(m_, bm);
      float alpha = __builtin_amdgcn_exp2f(m_ - mn);
      l_ *= alpha;
#pragma unroll
      for (int t = 0; t < 2; t++)
#pragma unroll
        for (int r = 0; r < 16; r++)
          accT[t][r] *= alpha;
      m_ = mn;
    }

    // P = exp2(S - m), pack to bf16 pairs, accumulate row sum
    uint32_t c8[8];
    float rs0 = 0.f, rs1 = 0.f;
#pragma unroll
    for (int i = 0; i < 8; i++){
      float p0 = __builtin_amdgcn_exp2f(s[2 * i]     - m_);
      float p1 = __builtin_amdgcn_exp2f(s[2 * i + 1] - m_);
      rs0 += p0; rs1 += p1;
      c8[i] = cvtpk_bf16(p0, p1);
    }
    float rs = rs0 + rs1;
    rs += __shfl_xor(rs, 32);
    l_ += rs;

    // redistribute: build P[q][kk] B-fragments via permlane32_swap (T12)
    plswap(c8[0], c8[2]); plswap(c8[1], c8[3]);
    plswap(c8[4], c8[6]); plswap(c8[5], c8[7]);
    union { uint32_t u[4]; bf16x8 v; } pf1, pf2;
    pf1.u[0] = c8[0]; pf1.u[1] = c8[1]; pf1.u[2] = c8[2]; pf1.u[3] = c8[3];
    pf2.u[0] = c8[4]; pf2.u[1] = c8[5]; pf2.u[2] = c8[6]; pf2.u[3] = c8[7];

    // O^T[d][q] += sum_kk V^T[d][kk] P[q][kk]
    accT[0] = __builtin_amdgcn_mfma_f32_32x32x16_bf16(vf[0][0], pf1.v, accT[0], 0, 0, 0);
    accT[0] = __builtin_amdgcn_mfma_f32_32x32x16_bf16(vf[0][1], pf2.v, accT[0], 0, 0, 0);
    accT[1] = __builtin_amdgcn_mfma_f32_32x32x16_bf16(vf[1][0], pf1.v, accT[1], 0, 0, 0);
    accT[1] = __builtin_amdgcn_mfma_f32_32x32x16_bf16(vf[1][1], pf2.v, accT[1], 0, 0, 0);
  }

  // ---- epilogue: normalize, transpose via per-wave LDS, coalesced stores ----
  float inv = 1.0f / l_;
  float* tw = &tl[w][0];
#pragma unroll
  for (int t = 0; t < 2; t++)
#pragma unroll
    for (int r = 0; r < 16; r++){
      int d = (r & 3) + 8 * (r >> 2) + 4 * hi + 32 * t;
      tw[d * 33 + ql] = accT[t][r] * inv;
    }
  asm volatile("s_waitcnt lgkmcnt(0)" ::: "memory");

  const int cq = lane >> 4;          // 0..3
  const int cc = (lane & 15) * 4;    // d base
#pragma unroll
  for (int it = 0; it < 8; it++){
    int q = it * 4 + cq;
    float4 o;
    o.x = tw[(cc + 0) * 33 + q];
    o.y = tw[(cc + 1) * 33 + q];
    o.z = tw[(cc + 2) * 33 + q];
    o.w = tw[(cc + 3) * 33 + q];
    *(float4*)(out + ((size_t)(b * T_SEQ + q0 + q)) * DMODEL + h * HS + cc) = o;
  }
}

extern "C" void kernel_launch(void* const* d_in, const int* in_sizes, int n_in,
                              void* d_out, int out_size, void* d_ws, size_t ws_size,
                              hipStream_t stream) {
  const float* x  = (const float*)d_in[0];
  const float* Wq = (const float*)d_in[1];
  const float* bq = (const float*)d_in[2];
  float* out = (float*)d_out;
  uint8_t* ws = (uint8_t*)d_ws;

  unsigned short* xb = (unsigned short*)(ws);
  unsigned short* wt = (unsigned short*)(ws + (size_t)16 * 1024 * 1024);
  unsigned short* Qb = (unsigned short*)(ws + (size_t)22 * 1024 * 1024);
  unsigned short* Kb = (unsigned short*)(ws + (size_t)38 * 1024 * 1024);
  unsigned short* Vt = (unsigned short*)(ws + (size_t)54 * 1024 * 1024);

  cvt_x<<<2048, 256, 0, stream>>>(x, xb, MTOT * DMODEL);
  cvt_wt<<<dim3(N3 / 32, DMODEL / 32), dim3(32, 8), 0, stream>>>(Wq, wt);
  gemm_qkv<<<dim3(MTOT / BM, N3 / BN), 256, 0, stream>>>(xb, wt, bq, Qb, Kb, Vt);
  attn<<<dim3(T_SEQ / 128, NHEAD, BSZ), 256, 0, stream>>>(Qb, Kb, Vt, out);
}

// Round 3
// 188.240 us; speedup vs baseline: 2.8652x; 1.6891x over previous
//
#include <hip/hip_runtime.h>
#include <stdint.h>

#define T_SEQ 2048
#define DMODEL 1024
#define NHEAD 16
#define HS 64
#define N3 3072
#define BSZ 4
#define MTOT (BSZ*T_SEQ)   // 8192

typedef __attribute__((ext_vector_type(8))) short bf16x8;
typedef __attribute__((ext_vector_type(4))) float f32x4;
typedef __attribute__((ext_vector_type(16))) float f32x16;
typedef __attribute__((ext_vector_type(2))) unsigned int uint2v;

// 0.125 (1/sqrt(64)) * log2(e): folded into Q so softmax runs in exp2 domain
#define QSCALE 0.18033688011112042f

// fragment-ordered Q/K/V: per (b,h): 64 kv/q tiles of 2048 ushorts (4KB)
// K/Q: value X[tile*32+ql][c*16+hi*8+e] at tile*2048 + c*512 + (hi*32+ql)*8 + e
// V:   value V[ts=tile*32+c*16+hi*8+e][d=t*32+ql] at tile*2048 + t*1024 + c*512 + (hi*32+ql)*8 + e
#define BH_STRIDE 131072  // 64 tiles * 2048 ushorts

__device__ inline unsigned short f2bf(float f){
  union { float f; uint32_t u; } v; v.f = f;
  uint32_t r = (v.u + 0x7fffu + ((v.u >> 16) & 1u)) >> 16;
  return (unsigned short)r;
}

__device__ inline uint32_t cvtpk_bf16(float lo, float hi){
  uint32_t r;
  asm("v_cvt_pk_bf16_f32 %0, %1, %2" : "=v"(r) : "v"(lo), "v"(hi));
  return r;
}

__device__ inline void plswap(uint32_t &a, uint32_t &b){
  uint2v r = __builtin_amdgcn_permlane32_swap(a, b, false, false);
  a = r[0]; b = r[1];
}

__device__ inline void gld16(const void* g, void* l){
  __builtin_amdgcn_global_load_lds((const __attribute__((address_space(1))) void*)g,
                                   (__attribute__((address_space(3))) void*)l, 16, 0, 0);
}

// ---- fp32 -> bf16 convert (x) ----
__global__ __launch_bounds__(256) void cvt_x(const float* __restrict__ x,
                                             unsigned short* __restrict__ xb, int n){
  int stride = gridDim.x * blockDim.x;
  for (int i = blockIdx.x * blockDim.x + threadIdx.x; i * 4 < n; i += stride){
    const float4 v = *(const float4*)(x + (size_t)i * 4);
    ushort4 o; o.x = f2bf(v.x); o.y = f2bf(v.y); o.z = f2bf(v.z); o.w = f2bf(v.w);
    *(ushort4*)(xb + (size_t)i * 4) = o;
  }
}

// ---- W [1024][3072] fp32 -> Wt [3072][1024] bf16 (tiled transpose) ----
__global__ __launch_bounds__(256) void cvt_wt(const float* __restrict__ W,
                                              unsigned short* __restrict__ Wt){
  __shared__ float tile[32][33];
  int bx = blockIdx.x;
  int by = blockIdx.y;
  int tx = threadIdx.x;
  int ty = threadIdx.y;
#pragma unroll
  for (int i = 0; i < 4; i++){
    int k = by * 32 + ty + i * 8;
    int n = bx * 32 + tx;
    tile[ty + i * 8][tx] = W[(size_t)k * N3 + n];
  }
  __syncthreads();
#pragma unroll
  for (int i = 0; i < 4; i++){
    int n = bx * 32 + ty + i * 8;
    int k = by * 32 + tx;
    Wt[(size_t)n * DMODEL + k] = f2bf(tile[tx][ty + i * 8]);
  }
}

// ---- QKV projection GEMM: C[8192][3072] = xb * Wt^T + bias, fragment-order scatter ----
#define BM 128
#define BN 128
#define BK 32

__global__ __launch_bounds__(256, 2) void gemm_qkv(
    const unsigned short* __restrict__ xb, const unsigned short* __restrict__ wt,
    const float* __restrict__ bias,
    unsigned short* __restrict__ Qb, unsigned short* __restrict__ Kb,
    unsigned short* __restrict__ Vt)
{
  __shared__ unsigned short Al[BM * BK];
  __shared__ unsigned short Bl[BN * BK];
  const int tid = threadIdx.x;
  const int lane = tid & 63;
  const int w  = tid >> 6;
  const int wm = w >> 1, wn = w & 1;
  const int lr = lane & 15, lg = lane >> 4;
  const int m0 = blockIdx.x * BM;
  const int n0 = blockIdx.y * BN;

  f32x4 acc[4][4] = {};

  const int srow = tid >> 2;
  const int scol = (tid & 3) * 8;
  const unsigned short* ga0 = xb + (size_t)(m0 + srow) * DMODEL + scol;
  const unsigned short* gb0 = wt + (size_t)(n0 + srow) * DMODEL + scol;
  unsigned short* la = &Al[tid * 8];
  unsigned short* lb = &Bl[tid * 8];

  for (int k0 = 0; k0 < DMODEL; k0 += BK){
    gld16(ga0 + k0, la);
    gld16(ga0 + k0 + (size_t)64 * DMODEL, la + 2048);
    gld16(gb0 + k0, lb);
    gld16(gb0 + k0 + (size_t)64 * DMODEL, lb + 2048);
    __syncthreads();
    bf16x8 af[4], bfg[4];
#pragma unroll
    for (int i = 0; i < 4; i++){
      af[i]  = *(const bf16x8*)&Al[(wm * 64 + i * 16 + lr) * BK + lg * 8];
      bfg[i] = *(const bf16x8*)&Bl[(wn * 64 + i * 16 + lr) * BK + lg * 8];
    }
#pragma unroll
    for (int i = 0; i < 4; i++)
#pragma unroll
      for (int j = 0; j < 4; j++)
        acc[i][j] = __builtin_amdgcn_mfma_f32_16x16x32_bf16(af[i], bfg[j], acc[i][j], 0, 0, 0);
    __syncthreads();
  }

#pragma unroll
  for (int i = 0; i < 4; i++){
#pragma unroll
    for (int j = 0; j < 4; j++){
      int gn = n0 + wn * 64 + j * 16 + lr;
      float bv = bias[gn];
      int h = gn / 192;
      int rem = gn - h * 192;
      int which = rem >> 6;
      int d = rem & 63;
#pragma unroll
      for (int r = 0; r < 4; r++){
        int gm = m0 + wm * 64 + i * 16 + lg * 4 + r;
        int b = gm >> 11, t = gm & 2047;
        float val = acc[i][j][r] + bv;
        size_t base = (size_t)(b * NHEAD + h) * BH_STRIDE + (size_t)(t >> 5) * 2048;
        if (which == 0)
          Qb[base + (d >> 4) * 512 + ((d >> 3) & 1) * 256 + (t & 31) * 8 + (d & 7)] = f2bf(val * QSCALE);
        else if (which == 1)
          Kb[base + (d >> 4) * 512 + ((d >> 3) & 1) * 256 + (t & 31) * 8 + (d & 7)] = f2bf(val);
        else {
          int kv = t & 31;
          Vt[base + (d >> 5) * 1024 + (kv >> 4) * 512 + ((kv >> 3) & 1) * 256 + (d & 31) * 8 + (kv & 7)] = f2bf(val);
        }
      }
    }
  }
}

// ---- flash attention, swapped-operand 32x32 MFMA, fragment-order coalesced loads ----
__global__ __launch_bounds__(256, 4) void attn(
    const unsigned short* __restrict__ Qb, const unsigned short* __restrict__ Kb,
    const unsigned short* __restrict__ Vt, float* __restrict__ out)
{
  __shared__ float tl[4][32 * 33];

  // XCD-bijective swizzle: 1024 wgs, 8 XCDs -> 128 contiguous work ids per XCD
  int flat = blockIdx.x + (blockIdx.y << 4) + (blockIdx.z << 8);
  int wid = (flat & 7) * 128 + (flat >> 3);
  const int bx = wid & 15;
  const int h  = (wid >> 4) & 15;
  const int b  = wid >> 8;

  const int tid = threadIdx.x;
  const int lane = tid & 63;
  const int w = tid >> 6;
  const int ql = lane & 31;
  const int bh = b * NHEAD + h;
  const int q0 = bx * 128 + w * 32;

  const unsigned short* Qf = Qb + (size_t)bh * BH_STRIDE;
  const unsigned short* Kf = Kb + (size_t)bh * BH_STRIDE;
  const unsigned short* Vf = Vt + (size_t)bh * BH_STRIDE;

  // Q fragments (B operand), coalesced: tile (q0>>5)
  bf16x8 qf[4];
#pragma unroll
  for (int c = 0; c < 4; c++)
    qf[c] = *(const bf16x8*)(Qf + (size_t)(q0 >> 5) * 2048 + c * 512 + lane * 8);

  f32x16 accT[2] = {};
  float m_ = -1e30f, l_ = 0.f;

  // K double-buffer in registers
  bf16x8 kA[4], kB[4];
#pragma unroll
  for (int c = 0; c < 4; c++)
    kA[c] = *(const bf16x8*)(Kf + c * 512 + lane * 8);

#define STEP(N_, KC, KN) { \
    const int n_ = (N_); \
    bf16x8 vf00 = *(const bf16x8*)(Vf + (size_t)n_ * 2048 +        lane * 8); \
    bf16x8 vf01 = *(const bf16x8*)(Vf + (size_t)n_ * 2048 +  512 + lane * 8); \
    bf16x8 vf10 = *(const bf16x8*)(Vf + (size_t)n_ * 2048 + 1024 + lane * 8); \
    bf16x8 vf11 = *(const bf16x8*)(Vf + (size_t)n_ * 2048 + 1536 + lane * 8); \
    f32x16 s = {}; \
    s = __builtin_amdgcn_mfma_f32_32x32x16_bf16(KC[0], qf[0], s, 0, 0, 0); \
    s = __builtin_amdgcn_mfma_f32_32x32x16_bf16(KC[1], qf[1], s, 0, 0, 0); \
    s = __builtin_amdgcn_mfma_f32_32x32x16_bf16(KC[2], qf[2], s, 0, 0, 0); \
    s = __builtin_amdgcn_mfma_f32_32x32x16_bf16(KC[3], qf[3], s, 0, 0, 0); \
    const int nn_ = (n_ + 1) & 63; \
    KN[0] = *(const bf16x8*)(Kf + (size_t)nn_ * 2048 +        lane * 8); \
    KN[1] = *(const bf16x8*)(Kf + (size_t)nn_ * 2048 +  512 + lane * 8); \
    KN[2] = *(const bf16x8*)(Kf + (size_t)nn_ * 2048 + 1024 + lane * 8); \
    KN[3] = *(const bf16x8*)(Kf + (size_t)nn_ * 2048 + 1536 + lane * 8); \
    float t0 = fmaxf(s[0], s[1]),  t1 = fmaxf(s[2], s[3]); \
    float t2 = fmaxf(s[4], s[5]),  t3 = fmaxf(s[6], s[7]); \
    float t4 = fmaxf(s[8], s[9]),  t5 = fmaxf(s[10], s[11]); \
    float t6 = fmaxf(s[12], s[13]), t7 = fmaxf(s[14], s[15]); \
    t0 = fmaxf(t0, t1); t2 = fmaxf(t2, t3); t4 = fmaxf(t4, t5); t6 = fmaxf(t6, t7); \
    t0 = fmaxf(t0, t2); t4 = fmaxf(t4, t6); \
    float bm = fmaxf(t0, t4); \
    bm = fmaxf(bm, __shfl_xor(bm, 32)); \
    if (!__all(bm <= m_ + 8.f)){ \
      float mn = fmaxf(m_, bm); \
      float alpha = __builtin_amdgcn_exp2f(m_ - mn); \
      l_ *= alpha; \
      _Pragma("unroll") \
      for (int t = 0; t < 2; t++) \
        _Pragma("unroll") \
        for (int r = 0; r < 16; r++) accT[t][r] *= alpha; \
      m_ = mn; \
    } \
    uint32_t c8[8]; \
    float rs0 = 0.f, rs1 = 0.f; \
    _Pragma("unroll") \
    for (int i = 0; i < 8; i++){ \
      float p0 = __builtin_amdgcn_exp2f(s[2 * i]     - m_); \
      float p1 = __builtin_amdgcn_exp2f(s[2 * i + 1] - m_); \
      rs0 += p0; rs1 += p1; \
      c8[i] = cvtpk_bf16(p0, p1); \
    } \
    float rs = rs0 + rs1; \
    rs += __shfl_xor(rs, 32); \
    l_ += rs; \
    plswap(c8[0], c8[2]); plswap(c8[1], c8[3]); \
    plswap(c8[4], c8[6]); plswap(c8[5], c8[7]); \
    union { uint32_t u[4]; bf16x8 v; } pf1, pf2; \
    pf1.u[0] = c8[0]; pf1.u[1] = c8[1]; pf1.u[2] = c8[2]; pf1.u[3] = c8[3]; \
    pf2.u[0] = c8[4]; pf2.u[1] = c8[5]; pf2.u[2] = c8[6]; pf2.u[3] = c8[7]; \
    accT[0] = __builtin_amdgcn_mfma_f32_32x32x16_bf16(vf00, pf1.v, accT[0], 0, 0, 0); \
    accT[0] = __builtin_amdgcn_mfma_f32_32x32x16_bf16(vf01, pf2.v, accT[0], 0, 0, 0); \
    accT[1] = __builtin_amdgcn_mfma_f32_32x32x16_bf16(vf10, pf1.v, accT[1], 0, 0, 0); \
    accT[1] = __builtin_amdgcn_mfma_f32_32x32x16_bf16(vf11, pf2.v, accT[1], 0, 0, 0); \
  }

  for (int n = 0; n < 64; n += 2){
    STEP(n,     kA, kB)
    STEP(n + 1, kB, kA)
  }
#undef STEP

  // ---- epilogue: normalize, transpose via per-wave LDS (two d-half passes) ----
  float inv = 1.0f / l_;
  float* tw = &tl[w][0];
  const int hi = lane >> 5;
#pragma unroll
  for (int t = 0; t < 2; t++){
#pragma unroll
    for (int r = 0; r < 16; r++){
      int dp = (r & 3) + 8 * (r >> 2) + 4 * hi;   // 0..31
      tw[dp * 33 + ql] = accT[t][r] * inv;
    }
    asm volatile("s_waitcnt lgkmcnt(0)" ::: "memory");
    const int cq = lane >> 3;          // 0..7
    const int cc = (lane & 7) * 4;     // d' base
#pragma unroll
    for (int it = 0; it < 4; it++){
      int q = it * 8 + cq;
      float4 o;
      o.x = tw[(cc + 0) * 33 + q];
      o.y = tw[(cc + 1) * 33 + q];
      o.z = tw[(cc + 2) * 33 + q];
      o.w = tw[(cc + 3) * 33 + q];
      *(float4*)(out + ((size_t)(b * T_SEQ + q0 + q)) * DMODEL + h * HS + t * 32 + cc) = o;
    }
    asm volatile("s_waitcnt lgkmcnt(0)" ::: "memory");
  }
}

extern "C" void kernel_launch(void* const* d_in, const int* in_sizes, int n_in,
                              void* d_out, int out_size, void* d_ws, size_t ws_size,
                              hipStream_t stream) {
  const float* x  = (const float*)d_in[0];
  const float* Wq = (const float*)d_in[1];
  const float* bq = (const float*)d_in[2];
  float* out = (float*)d_out;
  uint8_t* ws = (uint8_t*)d_ws;

  unsigned short* xb = (unsigned short*)(ws);
  unsigned short* wt = (unsigned short*)(ws + (size_t)16 * 1024 * 1024);
  unsigned short* Qb = (unsigned short*)(ws + (size_t)22 * 1024 * 1024);
  unsigned short* Kb = (unsigned short*)(ws + (size_t)38 * 1024 * 1024);
  unsigned short* Vt = (unsigned short*)(ws + (size_t)54 * 1024 * 1024);

  cvt_x<<<2048, 256, 0, stream>>>(x, xb, MTOT * DMODEL);
  cvt_wt<<<dim3(N3 / 32, DMODEL / 32), dim3(32, 8), 0, stream>>>(Wq, wt);
  gemm_qkv<<<dim3(MTOT / BM, N3 / BN), 256, 0, stream>>>(xb, wt, bq, Qb, Kb, Vt);
  attn<<<dim3(T_SEQ / 128, NHEAD, BSZ), 256, 0, stream>>>(Qb, Kb, Vt, out);
}

// Round 4
// 186.122 us; speedup vs baseline: 2.8978x; 1.0114x over previous
//
#include <hip/hip_runtime.h>
#include <stdint.h>

#define T_SEQ 2048
#define DMODEL 1024
#define NHEAD 16
#define HS 64
#define N3 3072
#define BSZ 4
#define MTOT (BSZ*T_SEQ)   // 8192

typedef __attribute__((ext_vector_type(8))) short bf16x8;
typedef __attribute__((ext_vector_type(4))) float f32x4;
typedef __attribute__((ext_vector_type(16))) float f32x16;
typedef __attribute__((ext_vector_type(2))) unsigned int uint2v;

// 0.125 (1/sqrt(64)) * log2(e): folded into Q so softmax runs in exp2 domain
#define QSCALE 0.18033688011112042f

// fragment-ordered Q/K/V: per (b,h): 64 kv/q tiles of 2048 ushorts (4KB)
#define BH_STRIDE 131072  // 64 tiles * 2048 ushorts

__device__ inline unsigned short f2bf(float f){
  union { float f; uint32_t u; } v; v.f = f;
  uint32_t r = (v.u + 0x7fffu + ((v.u >> 16) & 1u)) >> 16;
  return (unsigned short)r;
}

__device__ inline uint32_t cvtpk_bf16(float lo, float hi){
  uint32_t r;
  asm("v_cvt_pk_bf16_f32 %0, %1, %2" : "=v"(r) : "v"(lo), "v"(hi));
  return r;
}

__device__ inline void plswap(uint32_t &a, uint32_t &b){
  uint2v r = __builtin_amdgcn_permlane32_swap(a, b, false, false);
  a = r[0]; b = r[1];
}

__device__ inline void gld16(const void* g, void* l){
  __builtin_amdgcn_global_load_lds((const __attribute__((address_space(1))) void*)g,
                                   (__attribute__((address_space(3))) void*)l, 16, 0, 0);
}

// ---- fp32 -> bf16 convert (x) ----
__global__ __launch_bounds__(256) void cvt_x(const float* __restrict__ x,
                                             unsigned short* __restrict__ xb, int n){
  int stride = gridDim.x * blockDim.x;
  for (int i = blockIdx.x * blockDim.x + threadIdx.x; i * 4 < n; i += stride){
    const float4 v = *(const float4*)(x + (size_t)i * 4);
    ushort4 o; o.x = f2bf(v.x); o.y = f2bf(v.y); o.z = f2bf(v.z); o.w = f2bf(v.w);
    *(ushort4*)(xb + (size_t)i * 4) = o;
  }
}

// ---- W [1024][3072] fp32 -> Wt [3072][1024] bf16 (tiled transpose) ----
__global__ __launch_bounds__(256) void cvt_wt(const float* __restrict__ W,
                                              unsigned short* __restrict__ Wt){
  __shared__ float tile[32][33];
  int bx = blockIdx.x;
  int by = blockIdx.y;
  int tx = threadIdx.x;
  int ty = threadIdx.y;
#pragma unroll
  for (int i = 0; i < 4; i++){
    int k = by * 32 + ty + i * 8;
    int n = bx * 32 + tx;
    tile[ty + i * 8][tx] = W[(size_t)k * N3 + n];
  }
  __syncthreads();
#pragma unroll
  for (int i = 0; i < 4; i++){
    int n = bx * 32 + ty + i * 8;
    int k = by * 32 + tx;
    Wt[(size_t)n * DMODEL + k] = f2bf(tile[tx][ty + i * 8]);
  }
}

// ---- QKV projection GEMM: C[8192][3072] = xb * Wt^T + bias, fragment-order scatter ----
#define BM 128
#define BN 128
#define BK 32

__global__ __launch_bounds__(256, 2) void gemm_qkv(
    const unsigned short* __restrict__ xb, const unsigned short* __restrict__ wt,
    const float* __restrict__ bias,
    unsigned short* __restrict__ Qb, unsigned short* __restrict__ Kb,
    unsigned short* __restrict__ Vt)
{
  __shared__ unsigned short Al[BM * BK];
  __shared__ unsigned short Bl[BN * BK];
  const int tid = threadIdx.x;
  const int lane = tid & 63;
  const int w  = tid >> 6;
  const int wm = w >> 1, wn = w & 1;
  const int lr = lane & 15, lg = lane >> 4;
  const int m0 = blockIdx.x * BM;
  const int n0 = blockIdx.y * BN;

  f32x4 acc[4][4] = {};

  const int srow = tid >> 2;
  const int scol = (tid & 3) * 8;
  const unsigned short* ga0 = xb + (size_t)(m0 + srow) * DMODEL + scol;
  const unsigned short* gb0 = wt + (size_t)(n0 + srow) * DMODEL + scol;
  unsigned short* la = &Al[tid * 8];
  unsigned short* lb = &Bl[tid * 8];

  for (int k0 = 0; k0 < DMODEL; k0 += BK){
    gld16(ga0 + k0, la);
    gld16(ga0 + k0 + (size_t)64 * DMODEL, la + 2048);
    gld16(gb0 + k0, lb);
    gld16(gb0 + k0 + (size_t)64 * DMODEL, lb + 2048);
    __syncthreads();
    bf16x8 af[4], bfg[4];
#pragma unroll
    for (int i = 0; i < 4; i++){
      af[i]  = *(const bf16x8*)&Al[(wm * 64 + i * 16 + lr) * BK + lg * 8];
      bfg[i] = *(const bf16x8*)&Bl[(wn * 64 + i * 16 + lr) * BK + lg * 8];
    }
#pragma unroll
    for (int i = 0; i < 4; i++)
#pragma unroll
      for (int j = 0; j < 4; j++)
        acc[i][j] = __builtin_amdgcn_mfma_f32_16x16x32_bf16(af[i], bfg[j], acc[i][j], 0, 0, 0);
    __syncthreads();
  }

#pragma unroll
  for (int i = 0; i < 4; i++){
#pragma unroll
    for (int j = 0; j < 4; j++){
      int gn = n0 + wn * 64 + j * 16 + lr;
      float bv = bias[gn];
      int h = gn / 192;
      int rem = gn - h * 192;
      int which = rem >> 6;
      int d = rem & 63;
#pragma unroll
      for (int r = 0; r < 4; r++){
        int gm = m0 + wm * 64 + i * 16 + lg * 4 + r;
        int b = gm >> 11, t = gm & 2047;
        float val = acc[i][j][r] + bv;
        size_t base = (size_t)(b * NHEAD + h) * BH_STRIDE + (size_t)(t >> 5) * 2048;
        if (which == 0)
          Qb[base + (d >> 4) * 512 + ((d >> 3) & 1) * 256 + (t & 31) * 8 + (d & 7)] = f2bf(val * QSCALE);
        else if (which == 1)
          Kb[base + (d >> 4) * 512 + ((d >> 3) & 1) * 256 + (t & 31) * 8 + (d & 7)] = f2bf(val);
        else {
          int kv = t & 31;
          Vt[base + (d >> 5) * 1024 + (kv >> 4) * 512 + ((kv >> 3) & 1) * 256 + (d & 31) * 8 + (kv & 7)] = f2bf(val);
        }
      }
    }
  }
}

// ---- flash attention, swapped-operand 32x32 MFMA, fragment-order coalesced loads ----
__global__ __launch_bounds__(256, 4) void attn(
    const unsigned short* __restrict__ Qb, const unsigned short* __restrict__ Kb,
    const unsigned short* __restrict__ Vt, float* __restrict__ out)
{
  __shared__ float tl[4][32 * 33];

  // XCD-bijective swizzle: 1024 wgs, 8 XCDs -> 128 contiguous work ids per XCD
  int flat = blockIdx.x + (blockIdx.y << 4) + (blockIdx.z << 8);
  int wid = (flat & 7) * 128 + (flat >> 3);
  const int bx = wid & 15;
  const int h  = (wid >> 4) & 15;
  const int b  = wid >> 8;

  const int tid = threadIdx.x;
  const int lane = tid & 63;
  const int w = tid >> 6;
  const int ql = lane & 31;
  const int bh = b * NHEAD + h;
  const int q0 = bx * 128 + w * 32;

  const unsigned short* Qf = Qb + (size_t)bh * BH_STRIDE;
  const unsigned short* Kf = Kb + (size_t)bh * BH_STRIDE;
  const unsigned short* Vf = Vt + (size_t)bh * BH_STRIDE;

  // Q fragments (B operand), coalesced
  bf16x8 qf[4];
#pragma unroll
  for (int c = 0; c < 4; c++)
    qf[c] = *(const bf16x8*)(Qf + (size_t)(q0 >> 5) * 2048 + c * 512 + lane * 8);

  f32x16 accT[2] = {};
  // defer-max in biased domain: s_biased = S_raw - m ; m starts at 0 (NOT -inf:
  // with THR=8 P<=2^8, l<=5e5 in f32 -- safe; avoids 1e30 absorption)
  float negm = 0.f, l_ = 0.f;

  // K double-buffer in registers; walking pointers for next-tile K and cur V
  bf16x8 kA[4], kB[4];
#pragma unroll
  for (int c = 0; c < 4; c++)
    kA[c] = *(const bf16x8*)(Kf + c * 512 + lane * 8);
  const unsigned short* kp2 = Kf + 2048 + lane * 8;  // next-tile K
  const unsigned short* vp  = Vf + lane * 8;         // current-tile V

#define STEP(KC, KN) { \
    bf16x8 vf00 = *(const bf16x8*)(vp); \
    bf16x8 vf01 = *(const bf16x8*)(vp + 512); \
    bf16x8 vf10 = *(const bf16x8*)(vp + 1024); \
    bf16x8 vf11 = *(const bf16x8*)(vp + 1536); \
    vp += 2048; \
    f32x16 s; \
    _Pragma("unroll") \
    for (int r = 0; r < 16; r++) s[r] = negm; \
    s = __builtin_amdgcn_mfma_f32_32x32x16_bf16(KC[0], qf[0], s, 0, 0, 0); \
    s = __builtin_amdgcn_mfma_f32_32x32x16_bf16(KC[1], qf[1], s, 0, 0, 0); \
    s = __builtin_amdgcn_mfma_f32_32x32x16_bf16(KC[2], qf[2], s, 0, 0, 0); \
    s = __builtin_amdgcn_mfma_f32_32x32x16_bf16(KC[3], qf[3], s, 0, 0, 0); \
    KN[0] = *(const bf16x8*)(kp2); \
    KN[1] = *(const bf16x8*)(kp2 + 512); \
    KN[2] = *(const bf16x8*)(kp2 + 1024); \
    KN[3] = *(const bf16x8*)(kp2 + 1536); \
    kp2 += 2048; \
    /* max over 16 biased scores: max3-fusible triples (8 ops) */ \
    float t0 = fmaxf(fmaxf(s[0],  s[1]),  s[2]); \
    float t1 = fmaxf(fmaxf(s[3],  s[4]),  s[5]); \
    float t2 = fmaxf(fmaxf(s[6],  s[7]),  s[8]); \
    float t3 = fmaxf(fmaxf(s[9],  s[10]), s[11]); \
    float t4 = fmaxf(fmaxf(s[12], s[13]), s[14]); \
    float u0 = fmaxf(fmaxf(t0, t1), s[15]); \
    float u1 = fmaxf(t2, t3); \
    float bm = fmaxf(fmaxf(u0, u1), t4); \
    bm = fmaxf(bm, __shfl_xor(bm, 32)); \
    if (!__all(bm <= 8.f)){ \
      float delta = fmaxf(bm, 0.f); \
      float alpha = __builtin_amdgcn_exp2f(-delta); \
      l_ *= alpha; \
      negm -= delta; \
      _Pragma("unroll") \
      for (int t = 0; t < 2; t++) \
        _Pragma("unroll") \
        for (int r = 0; r < 16; r++) accT[t][r] *= alpha; \
      _Pragma("unroll") \
      for (int r = 0; r < 16; r++) s[r] -= delta; \
    } \
    uint32_t c8[8]; \
    float rsA = 0.f, rsB = 0.f, rsC = 0.f, rsD = 0.f; \
    _Pragma("unroll") \
    for (int i = 0; i < 8; i += 2){ \
      float p0 = __builtin_amdgcn_exp2f(s[2 * i]); \
      float p1 = __builtin_amdgcn_exp2f(s[2 * i + 1]); \
      float p2 = __builtin_amdgcn_exp2f(s[2 * i + 2]); \
      float p3 = __builtin_amdgcn_exp2f(s[2 * i + 3]); \
      rsA += p0; rsB += p1; rsC += p2; rsD += p3; \
      c8[i]     = cvtpk_bf16(p0, p1); \
      c8[i + 1] = cvtpk_bf16(p2, p3); \
    } \
    float rs = (rsA + rsB) + (rsC + rsD); \
    rs += __shfl_xor(rs, 32); \
    l_ += rs; \
    plswap(c8[0], c8[2]); plswap(c8[1], c8[3]); \
    plswap(c8[4], c8[6]); plswap(c8[5], c8[7]); \
    union { uint32_t u[4]; bf16x8 v; } pf1, pf2; \
    pf1.u[0] = c8[0]; pf1.u[1] = c8[1]; pf1.u[2] = c8[2]; pf1.u[3] = c8[3]; \
    pf2.u[0] = c8[4]; pf2.u[1] = c8[5]; pf2.u[2] = c8[6]; pf2.u[3] = c8[7]; \
    accT[0] = __builtin_amdgcn_mfma_f32_32x32x16_bf16(vf00, pf1.v, accT[0], 0, 0, 0); \
    accT[0] = __builtin_amdgcn_mfma_f32_32x32x16_bf16(vf01, pf2.v, accT[0], 0, 0, 0); \
    accT[1] = __builtin_amdgcn_mfma_f32_32x32x16_bf16(vf10, pf1.v, accT[1], 0, 0, 0); \
    accT[1] = __builtin_amdgcn_mfma_f32_32x32x16_bf16(vf11, pf2.v, accT[1], 0, 0, 0); \
  }

  for (int n = 0; n < 64; n += 2){
    STEP(kA, kB)
    STEP(kB, kA)
  }
#undef STEP

  // ---- epilogue: normalize, transpose via per-wave LDS (two d-half passes) ----
  float inv = 1.0f / l_;
  float* tw = &tl[w][0];
  const int hi = lane >> 5;
#pragma unroll
  for (int t = 0; t < 2; t++){
#pragma unroll
    for (int r = 0; r < 16; r++){
      int dp = (r & 3) + 8 * (r >> 2) + 4 * hi;   // 0..31
      tw[dp * 33 + ql] = accT[t][r] * inv;
    }
    asm volatile("s_waitcnt lgkmcnt(0)" ::: "memory");
    const int cq = lane >> 3;          // 0..7
    const int cc = (lane & 7) * 4;     // d' base
#pragma unroll
    for (int it = 0; it < 4; it++){
      int q = it * 8 + cq;
      float4 o;
      o.x = tw[(cc + 0) * 33 + q];
      o.y = tw[(cc + 1) * 33 + q];
      o.z = tw[(cc + 2) * 33 + q];
      o.w = tw[(cc + 3) * 33 + q];
      *(float4*)(out + ((size_t)(b * T_SEQ + q0 + q)) * DMODEL + h * HS + t * 32 + cc) = o;
    }
    asm volatile("s_waitcnt lgkmcnt(0)" ::: "memory");
  }
}

extern "C" void kernel_launch(void* const* d_in, const int* in_sizes, int n_in,
                              void* d_out, int out_size, void* d_ws, size_t ws_size,
                              hipStream_t stream) {
  const float* x  = (const float*)d_in[0];
  const float* Wq = (const float*)d_in[1];
  const float* bq = (const float*)d_in[2];
  float* out = (float*)d_out;
  uint8_t* ws = (uint8_t*)d_ws;

  unsigned short* xb = (unsigned short*)(ws);
  unsigned short* wt = (unsigned short*)(ws + (size_t)16 * 1024 * 1024);
  unsigned short* Qb = (unsigned short*)(ws + (size_t)22 * 1024 * 1024);
  unsigned short* Kb = (unsigned short*)(ws + (size_t)38 * 1024 * 1024);
  unsigned short* Vt = (unsigned short*)(ws + (size_t)54 * 1024 * 1024);

  cvt_x<<<2048, 256, 0, stream>>>(x, xb, MTOT * DMODEL);
  cvt_wt<<<dim3(N3 / 32, DMODEL / 32), dim3(32, 8), 0, stream>>>(Wq, wt);
  gemm_qkv<<<dim3(MTOT / BM, N3 / BN), 256, 0, stream>>>(xb, wt, bq, Qb, Kb, Vt);
  attn<<<dim3(T_SEQ / 128, NHEAD, BSZ), 256, 0, stream>>>(Qb, Kb, Vt, out);
}